// Round 1
// 365.339 us; speedup vs baseline: 1.5466x; 1.5466x over previous
//
#include <hip/hip_runtime.h>
#include <hip/hip_fp16.h>

// ComplexWindowAttn: B=2048 windows, DIM=96, HEADS=6, HEAD_DIM=16, N=64 (8x8).
// R8: full MFMA attention+proj.
//   K1: prep — qkv weights -> f16 planes; proj weights -> packed f16
//       Wp[96][192] ([wr | -wi] per head along K); rel -> expanded [6][64][64].
//   K2: per-window qkv cGEMM on mfma_f32_16x16x32_f16 (unchanged, verified R7).
//   K3: attention+proj all on MFMA:
//       S_r = [Qr|Qi]·[Kr|Ki]^T, S_i = [Qi|-Qr]·[Kr|Ki]^T  (K=32, one MFMA/tile)
//       magnitude-softmax in fp32 C-fragments (shfl_xor + 128-float LDS partials)
//       O_r = Ar·Vr + Ai·(-Vi), O_i = Ar·Vi + Ai·Vr        (K=64)
//       y   = [Or|Oi]·Wp^T accumulated across heads         (K=32/head)
// Fallback: verified R6 fused scalar kernel if ws too small.

#define HEADS 6
#define BLOCK 512
#define SCALE 0.25f

typedef _Float16 f16x8 __attribute__((ext_vector_type(8)));
typedef float    f32x4 __attribute__((ext_vector_type(4)));

#define WQ_ELEMS   27648              // 288*96 per plane
#define WS_WQ_B    165888             // 3 planes * 27648 * 2B
#define WS_WP_B    36864              // 96*192 f16
#define WS_REL_B   98304              // 6*64*64 f32
#define WS_WP_OFF  WS_WQ_B
#define WS_REL_OFF (WS_WQ_B + WS_WP_B)
#define WS_QKV_OFF (WS_WQ_B + WS_WP_B + WS_REL_B)
#define XT_PITCH   104                // 96 + 8 pad (keeps 16B alignment)

// ===================== K1: weight/bias preparation =====================
__global__ void prep_kernel(const float* __restrict__ wr,
                            const float* __restrict__ wi,
                            const float* __restrict__ pwr,
                            const float* __restrict__ pwi,
                            const float* __restrict__ rel,
                            __half* __restrict__ wq,
                            __half* __restrict__ wp,
                            float* __restrict__ rel_exp)
{
    int i = blockIdx.x * 256 + threadIdx.x;
    if (i < WQ_ELEMS) {
        wq[i]                 = __float2half(wr[i]);
        wq[WQ_ELEMS + i]      = __float2half(wi[i]);
        wq[2 * WQ_ELEMS + i]  = __float2half(-wi[i]);
    }
    if (i < 9216) {                       // 96*96 proj weights -> packed
        int o = i / 96, c = i - o * 96;
        int h = c >> 4, d = c & 15;
        wp[o * 192 + h * 32 + d]      = __float2half(pwr[i]);
        wp[o * 192 + h * 32 + 16 + d] = __float2half(-pwi[i]);
    }
    if (i < 24576) {                      // 6*64*64 expanded rel bias
        int h = i >> 12, r = (i >> 6) & 63, c = i & 63;
        int idx = ((r >> 3) - (c >> 3) + 7) * 15 + ((r & 7) - (c & 7) + 7);
        rel_exp[i] = rel[h * 225 + idx];
    }
}

// ===================== K2: qkv complex GEMM via MFMA (verified R7) ==========
__global__ __launch_bounds__(BLOCK) void qkv_mfma_kernel(
    const float* __restrict__ x_real, const float* __restrict__ x_imag,
    const __half* __restrict__ wq, unsigned* __restrict__ qkvp)
{
    __shared__ __align__(16) _Float16 xtr_r[64 * XT_PITCH];
    __shared__ __align__(16) _Float16 xtr_i[64 * XT_PITCH];

    const int b = blockIdx.x, t = threadIdx.x;
    const float* xr = x_real + (size_t)b * 6144;   // [c][n]
    const float* xi = x_imag + (size_t)b * 6144;

    for (int i = t; i < 6144; i += BLOCK) {
        int c = i >> 6, n = i & 63;
        xtr_r[n * XT_PITCH + c] = (_Float16)xr[i];
        xtr_i[n * XT_PITCH + c] = (_Float16)xi[i];
    }
    __syncthreads();

    const int w    = __builtin_amdgcn_readfirstlane(t >> 6);
    const int lane = t & 63;
    const int l16  = lane & 15;
    const int quad = lane >> 4;

    const __half* wr_p  = wq;
    const __half* wi_p  = wq + WQ_ELEMS;
    const __half* wni_p = wq + 2 * WQ_ELEMS;
    unsigned* dst = qkvp + (size_t)b * 288 * 64;

    int mts[3]; int nmt = 2;
    mts[0] = w * 2; mts[1] = w * 2 + 1;
    if (w < 2) { mts[2] = 16 + w; nmt = 3; }

    for (int mi = 0; mi < nmt; ++mi) {
        const int mt = mts[mi];
        f16x8 a_r[3], a_i[3], a_ni[3];
#pragma unroll
        for (int ks = 0; ks < 3; ++ks) {
            size_t off = (size_t)(mt * 16 + l16) * 96 + ks * 32 + quad * 8;
            a_r[ks]  = *reinterpret_cast<const f16x8*>(wr_p  + off);
            a_i[ks]  = *reinterpret_cast<const f16x8*>(wi_p  + off);
            a_ni[ks] = *reinterpret_cast<const f16x8*>(wni_p + off);
        }
#pragma unroll
        for (int nt = 0; nt < 4; ++nt) {
            const int n0 = nt * 16;
            f16x8 b_r[3], b_i[3];
#pragma unroll
            for (int ks = 0; ks < 3; ++ks) {
                int addr = (n0 + l16) * XT_PITCH + ks * 32 + quad * 8;
                b_r[ks] = *reinterpret_cast<const f16x8*>(&xtr_r[addr]);
                b_i[ks] = *reinterpret_cast<const f16x8*>(&xtr_i[addr]);
            }
            f32x4 accr = {0.f, 0.f, 0.f, 0.f};
            f32x4 acci = {0.f, 0.f, 0.f, 0.f};
#pragma unroll
            for (int ks = 0; ks < 3; ++ks) {
                accr = __builtin_amdgcn_mfma_f32_16x16x32_f16(a_r[ks],  b_r[ks], accr, 0, 0, 0);
                accr = __builtin_amdgcn_mfma_f32_16x16x32_f16(a_ni[ks], b_i[ks], accr, 0, 0, 0);
                acci = __builtin_amdgcn_mfma_f32_16x16x32_f16(a_r[ks],  b_i[ks], acci, 0, 0, 0);
                acci = __builtin_amdgcn_mfma_f32_16x16x32_f16(a_i[ks],  b_r[ks], acci, 0, 0, 0);
            }
#pragma unroll
            for (int r = 0; r < 4; ++r) {
                int o = mt * 16 + quad * 4 + r;
                int n = n0 + l16;
                __half2 p = __floats2half2_rn(accr[r], acci[r]);
                dst[(size_t)o * 64 + n] = *reinterpret_cast<unsigned*>(&p);
            }
        }
    }
}

// ===================== K3: MFMA attention + real-part proj ==================
// LDS pitches: sQ/sK/sO rows = 40 f16 (80B, 16B-aligned, b128 reads hit the
// 8-lanes-per-4-bank floor); sV/sA rows = 72 f16 (144B, same property).
__global__ __launch_bounds__(BLOCK) void attn_proj_mfma_kernel(
    const unsigned* __restrict__ qkvp,
    const __half* __restrict__ wp,
    const float* __restrict__ rel_exp,
    float* __restrict__ out)
{
    __shared__ __align__(16) _Float16 sQ [64 * 40];  // [n][ re(16) | im(16) ] *SCALE
    __shared__ __align__(16) _Float16 sK [64 * 40];  // [m][ re(16) | im(16) ]
    __shared__ __align__(16) _Float16 sVr[16 * 72];  // [d][m]
    __shared__ __align__(16) _Float16 sVi[16 * 72];
    __shared__ __align__(16) _Float16 sAr[64 * 72];  // [n][m] softmaxed attn
    __shared__ __align__(16) _Float16 sAi[64 * 72];
    __shared__ __align__(16) _Float16 sO [64 * 40];  // [n][ Or(16) | Oi(16) ]
    __shared__ float pmax[128];                      // [row][col-pair]
    __shared__ float psum[128];

    const int b    = blockIdx.x;
    const int t    = threadIdx.x;
    const int lane = t & 63;
    const int wave = __builtin_amdgcn_readfirstlane(t >> 6);
    const int l16  = lane & 15;
    const int quad = lane >> 4;

    const int rw = wave >> 1;     // 16-row block (0..3): scores/PV/proj rows
    const int cp = wave & 1;      // scores: col-pair; PV: re/im; proj: ob-triple

    const unsigned* src = qkvp + (size_t)b * 288 * 64;

    const int qk_dp = t & 7,  qk_n = t >> 3;   // q/k staging: (d-pair, n)
    const int v_np  = t & 31, v_d  = t >> 5;   // v staging:   (n-pair, d)

    f32x4 pacc0 = {0.f,0.f,0.f,0.f};
    f32x4 pacc1 = {0.f,0.f,0.f,0.f};
    f32x4 pacc2 = {0.f,0.f,0.f,0.f};

    const __half2 sch = __floats2half2_rn(SCALE, SCALE);

    for (int h = 0; h < HEADS; ++h) {
        // ---- hoisted head-constant loads (hide under staging+barrier) ----
        float bias_[2][4];
#pragma unroll
        for (int c2 = 0; c2 < 2; ++c2)
#pragma unroll
            for (int r = 0; r < 4; ++r)
                bias_[c2][r] = rel_exp[h * 4096 + (rw * 16 + quad * 4 + r) * 64
                                       + (cp * 2 + c2) * 16 + l16];
        const __half* wb = wp + h * 32 + quad * 8;
        const int ob0 = cp * 3;
        f16x8 wb0 = *reinterpret_cast<const f16x8*>(wb + ((ob0    ) * 16 + l16) * 192);
        f16x8 wb1 = *reinterpret_cast<const f16x8*>(wb + ((ob0 + 1) * 16 + l16) * 192);
        f16x8 wb2 = *reinterpret_cast<const f16x8*>(wb + ((ob0 + 2) * 16 + l16) * 192);

        // ---------- stage q,k,v ----------
        {
            const unsigned* sq_ = src + (h * 16) * 64;
            const unsigned* sk_ = sq_ + 96 * 64;
            const unsigned* sv_ = sq_ + 192 * 64;

            unsigned u0 = sq_[(2 * qk_dp) * 64 + qk_n];
            unsigned u1 = sq_[(2 * qk_dp + 1) * 64 + qk_n];
            __half2 A  = *reinterpret_cast<const __half2*>(&u0);
            __half2 Bv = *reinterpret_cast<const __half2*>(&u1);
            A = __hmul2(A, sch); Bv = __hmul2(Bv, sch);
            __half2 re, im;
            re.x = A.x; re.y = Bv.x; im.x = A.y; im.y = Bv.y;
            *reinterpret_cast<unsigned*>(&sQ[qk_n * 40 + 2 * qk_dp])      = *reinterpret_cast<unsigned*>(&re);
            *reinterpret_cast<unsigned*>(&sQ[qk_n * 40 + 16 + 2 * qk_dp]) = *reinterpret_cast<unsigned*>(&im);

            u0 = sk_[(2 * qk_dp) * 64 + qk_n];
            u1 = sk_[(2 * qk_dp + 1) * 64 + qk_n];
            A  = *reinterpret_cast<const __half2*>(&u0);
            Bv = *reinterpret_cast<const __half2*>(&u1);
            re.x = A.x; re.y = Bv.x; im.x = A.y; im.y = Bv.y;
            *reinterpret_cast<unsigned*>(&sK[qk_n * 40 + 2 * qk_dp])      = *reinterpret_cast<unsigned*>(&re);
            *reinterpret_cast<unsigned*>(&sK[qk_n * 40 + 16 + 2 * qk_dp]) = *reinterpret_cast<unsigned*>(&im);

            u0 = sv_[v_d * 64 + 2 * v_np];
            u1 = sv_[v_d * 64 + 2 * v_np + 1];
            A  = *reinterpret_cast<const __half2*>(&u0);
            Bv = *reinterpret_cast<const __half2*>(&u1);
            re.x = A.x; re.y = Bv.x; im.x = A.y; im.y = Bv.y;
            *reinterpret_cast<unsigned*>(&sVr[v_d * 72 + 2 * v_np]) = *reinterpret_cast<unsigned*>(&re);
            *reinterpret_cast<unsigned*>(&sVi[v_d * 72 + 2 * v_np]) = *reinterpret_cast<unsigned*>(&im);
        }
        __syncthreads();

        // ---------- scores + bias + magnitude ----------
        float sr[2][4], si[2][4], mg[2][4], ee[2][4];
        {
            const _Float16* qrow = &sQ[(rw * 16 + l16) * 40];
            f16x8 ar = *reinterpret_cast<const f16x8*>(qrow + quad * 8);
            // [Qi | -Qr] fragment: swap k-chunks, negate the Qr half
            f16x8 ab = *reinterpret_cast<const f16x8*>(qrow + ((quad + 2) & 3) * 8);
            if (quad >= 2) ab = -ab;
#pragma unroll
            for (int c2 = 0; c2 < 2; ++c2) {
                const int cb = cp * 2 + c2;
                f16x8 bk = *reinterpret_cast<const f16x8*>(&sK[(cb * 16 + l16) * 40 + quad * 8]);
                f32x4 fr = {0.f,0.f,0.f,0.f}, fi = {0.f,0.f,0.f,0.f};
                fr = __builtin_amdgcn_mfma_f32_16x16x32_f16(ar, bk, fr, 0, 0, 0);
                fi = __builtin_amdgcn_mfma_f32_16x16x32_f16(ab, bk, fi, 0, 0, 0);
#pragma unroll
                for (int r = 0; r < 4; ++r) {
                    float vr_ = fr[r] + bias_[c2][r];
                    float vi_ = fi[r];
                    sr[c2][r] = vr_; si[c2][r] = vi_;
                    mg[c2][r] = sqrtf(fmaf(vr_, vr_, vi_ * vi_));
                }
            }
            // partial row-max over this wave's 32 cols
#pragma unroll
            for (int r = 0; r < 4; ++r) {
                float m = fmaxf(mg[0][r], mg[1][r]);
                m = fmaxf(m, __shfl_xor(m, 1));
                m = fmaxf(m, __shfl_xor(m, 2));
                m = fmaxf(m, __shfl_xor(m, 4));
                m = fmaxf(m, __shfl_xor(m, 8));
                if (l16 == 0) pmax[(rw * 16 + quad * 4 + r) * 2 + cp] = m;
            }
        }
        __syncthreads();
        {
#pragma unroll
            for (int r = 0; r < 4; ++r) {
                const int row = rw * 16 + quad * 4 + r;
                const float mx = fmaxf(pmax[row * 2], pmax[row * 2 + 1]);
                float s = 0.f;
#pragma unroll
                for (int c2 = 0; c2 < 2; ++c2) {
                    ee[c2][r] = __expf(mg[c2][r] - mx);
                    s += ee[c2][r];
                }
                s += __shfl_xor(s, 1);
                s += __shfl_xor(s, 2);
                s += __shfl_xor(s, 4);
                s += __shfl_xor(s, 8);
                if (l16 == 0) psum[row * 2 + cp] = s;
            }
        }
        __syncthreads();
        {
#pragma unroll
            for (int r = 0; r < 4; ++r) {
                const int row = rw * 16 + quad * 4 + r;
                const float inv = 1.0f / (psum[row * 2] + psum[row * 2 + 1]);
#pragma unroll
                for (int c2 = 0; c2 < 2; ++c2) {
                    const int col = (cp * 2 + c2) * 16 + l16;
                    float f = ee[c2][r] * inv / (mg[c2][r] + 1e-8f);
                    sAr[row * 72 + col] = (_Float16)(sr[c2][r] * f);
                    sAi[row * 72 + col] = (_Float16)(si[c2][r] * f);
                }
            }
        }
        __syncthreads();

        // ---------- PV ----------
        {
            f32x4 oa = {0.f,0.f,0.f,0.f};
            const _Float16* arow = &sAr[(rw * 16 + l16) * 72];
            const _Float16* irow = &sAi[(rw * 16 + l16) * 72];
#pragma unroll
            for (int ks = 0; ks < 2; ++ks) {
                const int ko = ks * 32 + quad * 8;
                f16x8 fa  = *reinterpret_cast<const f16x8*>(arow + ko);
                f16x8 fai = *reinterpret_cast<const f16x8*>(irow + ko);
                f16x8 vr_ = *reinterpret_cast<const f16x8*>(&sVr[l16 * 72 + ko]);
                f16x8 vi_ = *reinterpret_cast<const f16x8*>(&sVi[l16 * 72 + ko]);
                if (cp == 0) {
                    oa = __builtin_amdgcn_mfma_f32_16x16x32_f16(fa, vr_, oa, 0, 0, 0);
                    oa = __builtin_amdgcn_mfma_f32_16x16x32_f16(fai, -vi_, oa, 0, 0, 0);
                } else {
                    oa = __builtin_amdgcn_mfma_f32_16x16x32_f16(fa, vi_, oa, 0, 0, 0);
                    oa = __builtin_amdgcn_mfma_f32_16x16x32_f16(fai, vr_, oa, 0, 0, 0);
                }
            }
#pragma unroll
            for (int r = 0; r < 4; ++r)
                sO[(rw * 16 + quad * 4 + r) * 40 + cp * 16 + l16] = (_Float16)oa[r];
        }
        __syncthreads();

        // ---------- proj (accumulated across heads) ----------
        {
            f16x8 a = *reinterpret_cast<const f16x8*>(&sO[(rw * 16 + l16) * 40 + quad * 8]);
            pacc0 = __builtin_amdgcn_mfma_f32_16x16x32_f16(a, wb0, pacc0, 0, 0, 0);
            pacc1 = __builtin_amdgcn_mfma_f32_16x16x32_f16(a, wb1, pacc1, 0, 0, 0);
            pacc2 = __builtin_amdgcn_mfma_f32_16x16x32_f16(a, wb2, pacc2, 0, 0, 0);
        }
        __syncthreads();
    }

    // ---------- epilogue: C col = o, row = n; 16B stores ----------
    {
        float* op = out + (size_t)b * 6144 + ((cp * 3) * 16 + l16) * 64
                  + rw * 16 + quad * 4;
        *reinterpret_cast<f32x4*>(op)           = pacc0;
        *reinterpret_cast<f32x4*>(op + 16 * 64) = pacc1;
        *reinterpret_cast<f32x4*>(op + 32 * 64) = pacc2;
    }
}

// ===================== Fallback: verified R6 fused kernel =====================
__global__ __launch_bounds__(BLOCK) void cwattn_kernel(
    const float* __restrict__ x_real, const float* __restrict__ x_imag,
    const float* __restrict__ qkv_wr, const float* __restrict__ qkv_wi,
    const float* __restrict__ proj_wr, const float* __restrict__ proj_wi,
    const float* __restrict__ rel, float* __restrict__ out,
    long long out_elems)
{
    __shared__ float2 qs[16 * 64];
    __shared__ float2 ks[16 * 64];
    __shared__ float2 vs[16 * 64];
    __shared__ float2 outh[16 * 64];

    const int b    = blockIdx.x;
    const int t    = threadIdx.x;
    const int lane = t & 63;
    const int wave = __builtin_amdgcn_readfirstlane(t >> 6);

    const float* xr = x_real + (size_t)b * 6144;
    const float* xi = x_imag + (size_t)b * 6144;

    float yr[12], yi[12];
#pragma unroll
    for (int j = 0; j < 12; ++j) { yr[j] = 0.f; yi[j] = 0.f; }

    const int g  = t >> 3;
    const int mo = t & 7;
    const int m0 = mo * 8;
    const int gi = g >> 3, gj = g & 7;

    for (int h = 0; h < HEADS; ++h) {
        {
            float ar[6], ai[6];
#pragma unroll
            for (int j = 0; j < 6; ++j) { ar[j] = 0.f; ai[j] = 0.f; }
            const int r0 = wave * 6;
            const float* wrp[6]; const float* wip[6];
#pragma unroll
            for (int j = 0; j < 6; ++j) {
                int r = r0 + j;
                int s = r >> 4;
                int o = s * 96 + h * 16 + (r & 15);
                wrp[j] = qkv_wr + o * 96;
                wip[j] = qkv_wi + o * 96;
            }
#pragma unroll 4
            for (int c = 0; c < 96; ++c) {
                float xre = xr[c * 64 + lane];
                float xim = xi[c * 64 + lane];
#pragma unroll
                for (int j = 0; j < 6; ++j) {
                    float wr = wrp[j][c], wi = wip[j][c];
                    ar[j] = fmaf(wr, xre, fmaf(-wi, xim, ar[j]));
                    ai[j] = fmaf(wr, xim, fmaf( wi, xre, ai[j]));
                }
            }
#pragma unroll
            for (int j = 0; j < 6; ++j) {
                int r  = r0 + j;
                int s  = r >> 4;
                int rd = r & 15;
                float scl   = (s == 0) ? SCALE : 1.0f;
                float2* dst = (s == 0) ? qs : ((s == 1) ? ks : vs);
                dst[rd * 64 + lane] = make_float2(ar[j] * scl, ai[j] * scl);
            }
        }
        __syncthreads();
        {
            float sr[8], si[8];
#pragma unroll
            for (int j = 0; j < 8; ++j) { sr[j] = 0.f; si[j] = 0.f; }
            for (int d = 0; d < 16; ++d) {
                float2 q2 = qs[d * 64 + g];
#pragma unroll
                for (int j = 0; j < 8; ++j) {
                    float2 k2 = ks[d * 64 + m0 + j];
                    sr[j] = fmaf(q2.x, k2.x, fmaf( q2.y, k2.y, sr[j]));
                    si[j] = fmaf(q2.y, k2.x, fmaf(-q2.x, k2.y, si[j]));
                }
            }
            const float* relh = rel + h * 225;
            float mag[8], e[8];
            float mx = -1e30f;
#pragma unroll
            for (int j = 0; j < 8; ++j) {
                int m = m0 + j;
                int idx = (gi - (m >> 3) + 7) * 15 + (gj - (m & 7) + 7);
                sr[j] += relh[idx];
                mag[j] = sqrtf(fmaf(sr[j], sr[j], si[j] * si[j]));
                mx = fmaxf(mx, mag[j]);
            }
            mx = fmaxf(mx, __shfl_xor(mx, 1));
            mx = fmaxf(mx, __shfl_xor(mx, 2));
            mx = fmaxf(mx, __shfl_xor(mx, 4));
            float ssum = 0.f;
#pragma unroll
            for (int j = 0; j < 8; ++j) { e[j] = __expf(mag[j] - mx); ssum += e[j]; }
            ssum += __shfl_xor(ssum, 1);
            ssum += __shfl_xor(ssum, 2);
            ssum += __shfl_xor(ssum, 4);
            float isum = 1.0f / ssum;
#pragma unroll
            for (int j = 0; j < 8; ++j) {
                float f = e[j] * isum / (mag[j] + 1e-8f);
                sr[j] *= f; si[j] *= f;
            }
            for (int d = 0; d < 16; ++d) {
                float pr = 0.f, pi = 0.f;
#pragma unroll
                for (int j = 0; j < 8; ++j) {
                    float2 v2 = vs[d * 64 + m0 + j];
                    pr = fmaf(sr[j], v2.x, fmaf(-si[j], v2.y, pr));
                    pi = fmaf(sr[j], v2.y, fmaf( si[j], v2.x, pi));
                }
                pr += __shfl_xor(pr, 1); pr += __shfl_xor(pr, 2); pr += __shfl_xor(pr, 4);
                pi += __shfl_xor(pi, 1); pi += __shfl_xor(pi, 2); pi += __shfl_xor(pi, 4);
                if (mo == 0) outh[d * 64 + g] = make_float2(pr, pi);
            }
        }
        __syncthreads();
        {
            const float* pr0 = proj_wr + (wave * 12) * 96 + h * 16;
            const float* pi0 = proj_wi + (wave * 12) * 96 + h * 16;
            for (int d = 0; d < 16; ++d) {
                float2 o2 = outh[d * 64 + lane];
#pragma unroll
                for (int j = 0; j < 12; ++j) {
                    float wr = pr0[j * 96 + d];
                    float wi = pi0[j * 96 + d];
                    yr[j] = fmaf(wr, o2.x, fmaf(-wi, o2.y, yr[j]));
                    yi[j] = fmaf(wr, o2.y, fmaf( wi, o2.x, yi[j]));
                }
            }
        }
        __syncthreads();
    }

    const long long n_total = (long long)gridDim.x * 6144;
#pragma unroll
    for (int j = 0; j < 12; ++j) {
        int o = wave * 12 + j;
        long long ci = (long long)b * 6144 + o * 64 + lane;
        if (ci < out_elems)           out[ci]           = yr[j];
        if (n_total + ci < out_elems) out[n_total + ci] = yi[j];
    }
}

// ===================== host =====================
extern "C" void kernel_launch(void* const* d_in, const int* in_sizes, int n_in,
                              void* d_out, int out_size, void* d_ws, size_t ws_size,
                              hipStream_t stream) {
    const float* x_real  = (const float*)d_in[0];
    const float* x_imag  = (const float*)d_in[1];
    const float* qkv_wr  = (const float*)d_in[2];
    const float* qkv_wi  = (const float*)d_in[3];
    const float* proj_wr = (const float*)d_in[4];
    const float* proj_wi = (const float*)d_in[5];
    const float* rel     = (const float*)d_in[6];
    float* out = (float*)d_out;

    const int B = in_sizes[0] / 6144;
    const size_t need = (size_t)WS_QKV_OFF + (size_t)B * 288 * 64 * 4;

    if (ws_size >= need) {
        __half*   wq      = (__half*)d_ws;
        __half*   wpq     = (__half*)((char*)d_ws + WS_WP_OFF);
        float*    rel_exp = (float*)((char*)d_ws + WS_REL_OFF);
        unsigned* qkvp    = (unsigned*)((char*)d_ws + WS_QKV_OFF);
        prep_kernel<<<(WQ_ELEMS + 255) / 256, 256, 0, stream>>>(
            qkv_wr, qkv_wi, proj_wr, proj_wi, rel, wq, wpq, rel_exp);
        qkv_mfma_kernel<<<B, BLOCK, 0, stream>>>(x_real, x_imag, wq, qkvp);
        attn_proj_mfma_kernel<<<B, BLOCK, 0, stream>>>(qkvp, wpq, rel_exp, out);
    } else {
        cwattn_kernel<<<B, BLOCK, 0, stream>>>(
            x_real, x_imag, qkv_wr, qkv_wi, proj_wr, proj_wi, rel, out,
            (long long)out_size);
    }
}

// Round 2
// 281.753 us; speedup vs baseline: 2.0055x; 1.2967x over previous
//
#include <hip/hip_runtime.h>
#include <hip/hip_fp16.h>

// ComplexWindowAttn: B=2048 windows, DIM=96, HEADS=6, HEAD_DIM=16, N=64 (8x8).
// R9: single fused MFMA kernel (qkv GEMM + attention + proj per window block).
//   prep: qkv weights -> f16 planes; proj weights -> packed f16 Wp[96][192]
//         ([wr | -wi] per head along K); rel -> TRANSPOSED [6][m=64][n=64] f32.
//   fused per block:
//     phase1: stage x^T as f16 into LDS (vectorized b128 writes).
//     phase2: qkv cGEMM (R7-verified MFMA loop, 72 (mt,nt) units over 8 waves),
//             epilogue writes straight to LDS: sQ/sK [h][n][re16|im16] (Q
//             pre-scaled), sV [h][d][m].
//     rounds (3 x 2 heads): swapped scores S^T = MFMA(A=K, B=Q) so each lane
//             owns fixed n=l16 and 16 m-slots -> softmax needs only 2 shfl_xor;
//             sA[n][m] write; PV + proj = R8-verified code. 2 barriers/round.
// Fallback: verified R6 fused scalar kernel if ws too small.

#define HEADS 6
#define BLOCK 512
#define SCALE 0.25f

typedef _Float16 f16x8 __attribute__((ext_vector_type(8)));
typedef float    f32x4 __attribute__((ext_vector_type(4)));

#define WQ_ELEMS   27648              // 288*96 per plane
#define WS_WQ_B    165888             // 3 planes * 27648 * 2B
#define WS_WP_B    36864              // 96*192 f16
#define WS_REL_B   98304              // 6*64*64 f32
#define WS_WP_OFF  WS_WQ_B
#define WS_REL_OFF (WS_WQ_B + WS_WP_B)
#define WS_NEED    (WS_WQ_B + WS_WP_B + WS_REL_B)
#define XT_PITCH   104                // 96 + 8 pad (keeps 16B alignment)

// ===================== K1: weight/bias preparation =====================
__global__ void prep_kernel(const float* __restrict__ wr,
                            const float* __restrict__ wi,
                            const float* __restrict__ pwr,
                            const float* __restrict__ pwi,
                            const float* __restrict__ rel,
                            __half* __restrict__ wq,
                            __half* __restrict__ wp,
                            float* __restrict__ rel_exp)
{
    int i = blockIdx.x * 256 + threadIdx.x;
    if (i < WQ_ELEMS) {
        wq[i]                 = __float2half(wr[i]);
        wq[WQ_ELEMS + i]      = __float2half(wi[i]);
        wq[2 * WQ_ELEMS + i]  = __float2half(-wi[i]);
    }
    if (i < 9216) {                       // 96*96 proj weights -> packed
        int o = i / 96, c = i - o * 96;
        int h = c >> 4, d = c & 15;
        wp[o * 192 + h * 32 + d]      = __float2half(pwr[i]);
        wp[o * 192 + h * 32 + 16 + d] = __float2half(-pwi[i]);
    }
    if (i < 24576) {                      // rel -> TRANSPOSED [h][m][n]
        int h = i >> 12, m = (i >> 6) & 63, n = i & 63;
        int idx = ((n >> 3) - (m >> 3) + 7) * 15 + ((n & 7) - (m & 7) + 7);
        rel_exp[i] = rel[h * 225 + idx];
    }
}

// ===================== fused kernel =====================
// LDS map (f16 units):
//   sQ  [6][64][40]   @ 0      (15360)   persistent  re@d, im@16+d, *SCALE
//   sK  [6][64][40]   @ 15360  (15360)   persistent
//   sVr [6][16][72]   @ 30720  (6912)    persistent  [d][m]
//   sVi [6][16][72]   @ 37632  (6912)
//   overlay @ 44544:
//     xtr_r [64][104] @ 44544  (6656)    qkv phase only
//     xtr_i [64][104] @ 51200  (6656)
//     sAr [2][64][72] @ 44544  (9216)    attn rounds
//     sAi [2][64][72] @ 53760  (9216)
//     sO  [2][64][40] @ 62976  (5120)    Or@d, Oi@16+d
// total 68096 f16 = 136192 B (1 block/CU)
__global__ __launch_bounds__(BLOCK) void fused_kernel(
    const float* __restrict__ x_real, const float* __restrict__ x_imag,
    const __half* __restrict__ wq,
    const __half* __restrict__ wp,
    const float* __restrict__ relT,
    float* __restrict__ out)
{
    __shared__ __align__(16) _Float16 smem[68096];

    _Float16* const sQp   = smem;
    _Float16* const sKp   = smem + 15360;
    _Float16* const sVrp  = smem + 30720;
    _Float16* const sVip  = smem + 37632;
    _Float16* const xtr_r = smem + 44544;
    _Float16* const xtr_i = smem + 51200;
    _Float16* const sArp  = smem + 44544;
    _Float16* const sAip  = smem + 53760;
    _Float16* const sOp   = smem + 62976;

    const int b    = blockIdx.x;
    const int t    = threadIdx.x;
    const int lane = t & 63;
    const int w    = __builtin_amdgcn_readfirstlane(t >> 6);
    const int l16  = lane & 15;
    const int quad = lane >> 4;

    const float* xr = x_real + (size_t)b * 6144;   // [c][n]
    const float* xi = x_imag + (size_t)b * 6144;

    // ---------- phase 1: stage x^T (f16, B^T layout) ----------
    {
        // pass 0: all threads: n = t>>3, cb = t&7   (c-blocks 0..7)
        // pass 1: t<256:       n = t>>2, cb = 8+(t&3) (c-blocks 8..11)
#pragma unroll
        for (int pass = 0; pass < 2; ++pass) {
            int n, cb;
            if (pass == 0) { n = t >> 3; cb = t & 7; }
            else           { if (t >= 256) break; n = t >> 2; cb = 8 + (t & 3); }
            const float* xrp = xr + cb * 512 + n;
            const float* xip = xi + cb * 512 + n;
            f16x8 vr, vi;
#pragma unroll
            for (int j = 0; j < 8; ++j) {
                vr[j] = (_Float16)xrp[j * 64];
                vi[j] = (_Float16)xip[j * 64];
            }
            *reinterpret_cast<f16x8*>(&xtr_r[n * XT_PITCH + cb * 8]) = vr;
            *reinterpret_cast<f16x8*>(&xtr_i[n * XT_PITCH + cb * 8]) = vi;
        }
    }
    __syncthreads();

    // ---------- phase 2: qkv cGEMM -> sQ/sK/sV ----------
    {
        const __half* wr_p  = wq;
        const __half* wi_p  = wq + WQ_ELEMS;
        const __half* wni_p = wq + 2 * WQ_ELEMS;

        int last_mt = -1;
        f16x8 a_r[3], a_i[3], a_ni[3];
        for (int ui = 0; ui < 9; ++ui) {
            const int u  = w * 9 + ui;
            const int mt = u >> 2, nt = u & 3;
            if (mt != last_mt) {
#pragma unroll
                for (int ks = 0; ks < 3; ++ks) {
                    size_t off = (size_t)(mt * 16 + l16) * 96 + ks * 32 + quad * 8;
                    a_r[ks]  = *reinterpret_cast<const f16x8*>(wr_p  + off);
                    a_i[ks]  = *reinterpret_cast<const f16x8*>(wi_p  + off);
                    a_ni[ks] = *reinterpret_cast<const f16x8*>(wni_p + off);
                }
                last_mt = mt;
            }
            const int n0 = nt * 16;
            f16x8 b_r[3], b_i[3];
#pragma unroll
            for (int ks = 0; ks < 3; ++ks) {
                int addr = (n0 + l16) * XT_PITCH + ks * 32 + quad * 8;
                b_r[ks] = *reinterpret_cast<const f16x8*>(&xtr_r[addr]);
                b_i[ks] = *reinterpret_cast<const f16x8*>(&xtr_i[addr]);
            }
            f32x4 accr = {0.f, 0.f, 0.f, 0.f};
            f32x4 acci = {0.f, 0.f, 0.f, 0.f};
#pragma unroll
            for (int ks = 0; ks < 3; ++ks) {
                accr = __builtin_amdgcn_mfma_f32_16x16x32_f16(a_r[ks],  b_r[ks], accr, 0, 0, 0);
                accr = __builtin_amdgcn_mfma_f32_16x16x32_f16(a_ni[ks], b_i[ks], accr, 0, 0, 0);
                acci = __builtin_amdgcn_mfma_f32_16x16x32_f16(a_r[ks],  b_i[ks], acci, 0, 0, 0);
                acci = __builtin_amdgcn_mfma_f32_16x16x32_f16(a_i[ks],  b_r[ks], acci, 0, 0, 0);
            }
            // C: col n = n0+l16, row o = mt*16 + quad*4 + r  (verified layout)
            const int n = n0 + l16;
            if (mt < 6) {                       // Q rows, pre-scaled
                _Float16* q = sQp + mt * 2560 + n * 40;
#pragma unroll
                for (int r = 0; r < 4; ++r) {
                    q[quad * 4 + r]      = (_Float16)(accr[r] * SCALE);
                    q[16 + quad * 4 + r] = (_Float16)(acci[r] * SCALE);
                }
            } else if (mt < 12) {               // K rows
                _Float16* kk = sKp + (mt - 6) * 2560 + n * 40;
#pragma unroll
                for (int r = 0; r < 4; ++r) {
                    kk[quad * 4 + r]      = (_Float16)accr[r];
                    kk[16 + quad * 4 + r] = (_Float16)acci[r];
                }
            } else {                            // V rows -> [d][m]
                const int hh2 = mt - 12;
#pragma unroll
                for (int r = 0; r < 4; ++r) {
                    sVrp[hh2 * 1152 + (quad * 4 + r) * 72 + n] = (_Float16)accr[r];
                    sVip[hh2 * 1152 + (quad * 4 + r) * 72 + n] = (_Float16)acci[r];
                }
            }
        }
    }
    __syncthreads();

    // ---------- attention rounds: 2 heads / round ----------
    f32x4 pacc0 = {0.f,0.f,0.f,0.f};
    f32x4 pacc1 = {0.f,0.f,0.f,0.f};
    f32x4 pacc2 = {0.f,0.f,0.f,0.f};

    const _Float16* wpf = reinterpret_cast<const _Float16*>(wp);

    for (int ro = 0; ro < 3; ++ro) {
        const int hr = w >> 2;          // head-in-round (0/1)
        const int nb = w & 3;           // 16-col n-block
        const int hh = ro * 2 + hr;     // global head

        // proj B-frags for both heads of this round (issued early, L2-hot)
        const int ob0 = (w & 1) * 3;
        f16x8 wbf0[2], wbf1[2], wbf2[2];
#pragma unroll
        for (int h2 = 0; h2 < 2; ++h2) {
            const _Float16* wb = wpf + (ro * 2 + h2) * 32 + quad * 8;
            wbf0[h2] = *reinterpret_cast<const f16x8*>(wb + ((ob0    ) * 16 + l16) * 192);
            wbf1[h2] = *reinterpret_cast<const f16x8*>(wb + ((ob0 + 1) * 16 + l16) * 192);
            wbf2[h2] = *reinterpret_cast<const f16x8*>(wb + ((ob0 + 2) * 16 + l16) * 192);
        }

        // ---- swapped scores: C[m][n], lane owns n = nb*16+l16 ----
        const _Float16* qrow = sQp + hh * 2560 + (nb * 16 + l16) * 40;
        f16x8 bq  = *reinterpret_cast<const f16x8*>(qrow + quad * 8);
        f16x8 bq2 = *reinterpret_cast<const f16x8*>(qrow + ((quad + 2) & 3) * 8);
        if (quad >= 2) bq2 = -bq2;      // [Qi | -Qr]

        float sr16[4][4], si16[4][4], mg16[4][4], ee16[4][4];
        float mx = -1e30f;
#pragma unroll
        for (int tm = 0; tm < 4; ++tm) {
            f16x8 ak = *reinterpret_cast<const f16x8*>(
                sKp + hh * 2560 + (tm * 16 + l16) * 40 + quad * 8);
            f32x4 fr = {0.f,0.f,0.f,0.f}, fi = {0.f,0.f,0.f,0.f};
            fr = __builtin_amdgcn_mfma_f32_16x16x32_f16(ak, bq,  fr, 0, 0, 0);
            fi = __builtin_amdgcn_mfma_f32_16x16x32_f16(ak, bq2, fi, 0, 0, 0);
#pragma unroll
            for (int r = 0; r < 4; ++r) {
                const int m = tm * 16 + quad * 4 + r;
                float bb  = relT[hh * 4096 + m * 64 + nb * 16 + l16];
                float vr_ = fr[r] + bb;
                float vi_ = fi[r];
                sr16[tm][r] = vr_; si16[tm][r] = vi_;
                float mgv = sqrtf(fmaf(vr_, vr_, vi_ * vi_));
                mg16[tm][r] = mgv;
                mx = fmaxf(mx, mgv);
            }
        }
        mx = fmaxf(mx, __shfl_xor(mx, 16));
        mx = fmaxf(mx, __shfl_xor(mx, 32));
        float ss = 0.f;
#pragma unroll
        for (int tm = 0; tm < 4; ++tm)
#pragma unroll
            for (int r = 0; r < 4; ++r) {
                ee16[tm][r] = __expf(mg16[tm][r] - mx);
                ss += ee16[tm][r];
            }
        ss += __shfl_xor(ss, 16);
        ss += __shfl_xor(ss, 32);
        const float inv = 1.0f / ss;

        _Float16* arw = sArp + hr * 4608 + (nb * 16 + l16) * 72;
        _Float16* aiw = sAip + hr * 4608 + (nb * 16 + l16) * 72;
#pragma unroll
        for (int tm = 0; tm < 4; ++tm)
#pragma unroll
            for (int r = 0; r < 4; ++r) {
                const int m = tm * 16 + quad * 4 + r;
                float f = ee16[tm][r] * inv / (mg16[tm][r] + 1e-8f);
                arw[m] = (_Float16)(sr16[tm][r] * f);
                aiw[m] = (_Float16)(si16[tm][r] * f);
            }
        __syncthreads();

        // ---- PV (R8-verified): O[n][d] ----
        {
            f32x4 oar = {0.f,0.f,0.f,0.f}, oai = {0.f,0.f,0.f,0.f};
            const _Float16* ar_ = sArp + hr * 4608 + (nb * 16 + l16) * 72;
            const _Float16* ai_ = sAip + hr * 4608 + (nb * 16 + l16) * 72;
#pragma unroll
            for (int ks = 0; ks < 2; ++ks) {
                const int ko = ks * 32 + quad * 8;
                f16x8 fa  = *reinterpret_cast<const f16x8*>(ar_ + ko);
                f16x8 fai = *reinterpret_cast<const f16x8*>(ai_ + ko);
                f16x8 vr_ = *reinterpret_cast<const f16x8*>(&sVrp[hh * 1152 + l16 * 72 + ko]);
                f16x8 vi_ = *reinterpret_cast<const f16x8*>(&sVip[hh * 1152 + l16 * 72 + ko]);
                oar = __builtin_amdgcn_mfma_f32_16x16x32_f16(fa,  vr_,  oar, 0, 0, 0);
                oar = __builtin_amdgcn_mfma_f32_16x16x32_f16(fai, -vi_, oar, 0, 0, 0);
                oai = __builtin_amdgcn_mfma_f32_16x16x32_f16(fa,  vi_,  oai, 0, 0, 0);
                oai = __builtin_amdgcn_mfma_f32_16x16x32_f16(fai, vr_,  oai, 0, 0, 0);
            }
#pragma unroll
            for (int r = 0; r < 4; ++r) {
                const int n = nb * 16 + quad * 4 + r;
                sOp[hr * 2560 + n * 40 + l16]      = (_Float16)oar[r];
                sOp[hr * 2560 + n * 40 + 16 + l16] = (_Float16)oai[r];
            }
        }
        __syncthreads();

        // ---- proj accumulate (R8-verified) ----
        {
            const int pnb = w >> 1;
#pragma unroll
            for (int h2 = 0; h2 < 2; ++h2) {
                f16x8 a = *reinterpret_cast<const f16x8*>(
                    sOp + h2 * 2560 + (pnb * 16 + l16) * 40 + quad * 8);
                pacc0 = __builtin_amdgcn_mfma_f32_16x16x32_f16(a, wbf0[h2], pacc0, 0, 0, 0);
                pacc1 = __builtin_amdgcn_mfma_f32_16x16x32_f16(a, wbf1[h2], pacc1, 0, 0, 0);
                pacc2 = __builtin_amdgcn_mfma_f32_16x16x32_f16(a, wbf2[h2], pacc2, 0, 0, 0);
            }
        }
        // next round's sA writes are ordered by this round's barriers; no
        // extra barrier needed (sA/sO disjoint, sO rewrite gated by next B1).
    }

    // ---------- epilogue: out[o][n], o = (w&1)*48 + j*16 + l16 ----------
    {
        float* op = out + (size_t)b * 6144 + ((w & 1) * 48 + l16) * 64
                  + (w >> 1) * 16 + quad * 4;
        *reinterpret_cast<f32x4*>(op)        = pacc0;
        *reinterpret_cast<f32x4*>(op + 1024) = pacc1;
        *reinterpret_cast<f32x4*>(op + 2048) = pacc2;
    }
}

// ===================== Fallback: verified R6 fused kernel =====================
__global__ __launch_bounds__(BLOCK) void cwattn_kernel(
    const float* __restrict__ x_real, const float* __restrict__ x_imag,
    const float* __restrict__ qkv_wr, const float* __restrict__ qkv_wi,
    const float* __restrict__ proj_wr, const float* __restrict__ proj_wi,
    const float* __restrict__ rel, float* __restrict__ out,
    long long out_elems)
{
    __shared__ float2 qs[16 * 64];
    __shared__ float2 ks[16 * 64];
    __shared__ float2 vs[16 * 64];
    __shared__ float2 outh[16 * 64];

    const int b    = blockIdx.x;
    const int t    = threadIdx.x;
    const int lane = t & 63;
    const int wave = __builtin_amdgcn_readfirstlane(t >> 6);

    const float* xr = x_real + (size_t)b * 6144;
    const float* xi = x_imag + (size_t)b * 6144;

    float yr[12], yi[12];
#pragma unroll
    for (int j = 0; j < 12; ++j) { yr[j] = 0.f; yi[j] = 0.f; }

    const int g  = t >> 3;
    const int mo = t & 7;
    const int m0 = mo * 8;
    const int gi = g >> 3, gj = g & 7;

    for (int h = 0; h < HEADS; ++h) {
        {
            float ar[6], ai[6];
#pragma unroll
            for (int j = 0; j < 6; ++j) { ar[j] = 0.f; ai[j] = 0.f; }
            const int r0 = wave * 6;
            const float* wrp[6]; const float* wip[6];
#pragma unroll
            for (int j = 0; j < 6; ++j) {
                int r = r0 + j;
                int s = r >> 4;
                int o = s * 96 + h * 16 + (r & 15);
                wrp[j] = qkv_wr + o * 96;
                wip[j] = qkv_wi + o * 96;
            }
#pragma unroll 4
            for (int c = 0; c < 96; ++c) {
                float xre = xr[c * 64 + lane];
                float xim = xi[c * 64 + lane];
#pragma unroll
                for (int j = 0; j < 6; ++j) {
                    float wr = wrp[j][c], wi = wip[j][c];
                    ar[j] = fmaf(wr, xre, fmaf(-wi, xim, ar[j]));
                    ai[j] = fmaf(wr, xim, fmaf( wi, xre, ai[j]));
                }
            }
#pragma unroll
            for (int j = 0; j < 6; ++j) {
                int r  = r0 + j;
                int s  = r >> 4;
                int rd = r & 15;
                float scl   = (s == 0) ? SCALE : 1.0f;
                float2* dst = (s == 0) ? qs : ((s == 1) ? ks : vs);
                dst[rd * 64 + lane] = make_float2(ar[j] * scl, ai[j] * scl);
            }
        }
        __syncthreads();
        {
            float sr[8], si[8];
#pragma unroll
            for (int j = 0; j < 8; ++j) { sr[j] = 0.f; si[j] = 0.f; }
            for (int d = 0; d < 16; ++d) {
                float2 q2 = qs[d * 64 + g];
#pragma unroll
                for (int j = 0; j < 8; ++j) {
                    float2 k2 = ks[d * 64 + m0 + j];
                    sr[j] = fmaf(q2.x, k2.x, fmaf( q2.y, k2.y, sr[j]));
                    si[j] = fmaf(q2.y, k2.x, fmaf(-q2.x, k2.y, si[j]));
                }
            }
            const float* relh = rel + h * 225;
            float mag[8], e[8];
            float mx = -1e30f;
#pragma unroll
            for (int j = 0; j < 8; ++j) {
                int m = m0 + j;
                int idx = (gi - (m >> 3) + 7) * 15 + (gj - (m & 7) + 7);
                sr[j] += relh[idx];
                mag[j] = sqrtf(fmaf(sr[j], sr[j], si[j] * si[j]));
                mx = fmaxf(mx, mag[j]);
            }
            mx = fmaxf(mx, __shfl_xor(mx, 1));
            mx = fmaxf(mx, __shfl_xor(mx, 2));
            mx = fmaxf(mx, __shfl_xor(mx, 4));
            float ssum = 0.f;
#pragma unroll
            for (int j = 0; j < 8; ++j) { e[j] = __expf(mag[j] - mx); ssum += e[j]; }
            ssum += __shfl_xor(ssum, 1);
            ssum += __shfl_xor(ssum, 2);
            ssum += __shfl_xor(ssum, 4);
            float isum = 1.0f / ssum;
#pragma unroll
            for (int j = 0; j < 8; ++j) {
                float f = e[j] * isum / (mag[j] + 1e-8f);
                sr[j] *= f; si[j] *= f;
            }
            for (int d = 0; d < 16; ++d) {
                float pr = 0.f, pi = 0.f;
#pragma unroll
                for (int j = 0; j < 8; ++j) {
                    float2 v2 = vs[d * 64 + m0 + j];
                    pr = fmaf(sr[j], v2.x, fmaf(-si[j], v2.y, pr));
                    pi = fmaf(sr[j], v2.y, fmaf( si[j], v2.x, pi));
                }
                pr += __shfl_xor(pr, 1); pr += __shfl_xor(pr, 2); pr += __shfl_xor(pr, 4);
                pi += __shfl_xor(pi, 1); pi += __shfl_xor(pi, 2); pi += __shfl_xor(pi, 4);
                if (mo == 0) outh[d * 64 + g] = make_float2(pr, pi);
            }
        }
        __syncthreads();
        {
            const float* pr0 = proj_wr + (wave * 12) * 96 + h * 16;
            const float* pi0 = proj_wi + (wave * 12) * 96 + h * 16;
            for (int d = 0; d < 16; ++d) {
                float2 o2 = outh[d * 64 + lane];
#pragma unroll
                for (int j = 0; j < 12; ++j) {
                    float wr = pr0[j * 96 + d];
                    float wi = pi0[j * 96 + d];
                    yr[j] = fmaf(wr, o2.x, fmaf(-wi, o2.y, yr[j]));
                    yi[j] = fmaf(wr, o2.y, fmaf( wi, o2.x, yi[j]));
                }
            }
        }
        __syncthreads();
    }

    const long long n_total = (long long)gridDim.x * 6144;
#pragma unroll
    for (int j = 0; j < 12; ++j) {
        int o = wave * 12 + j;
        long long ci = (long long)b * 6144 + o * 64 + lane;
        if (ci < out_elems)           out[ci]           = yr[j];
        if (n_total + ci < out_elems) out[n_total + ci] = yi[j];
    }
}

// ===================== host =====================
extern "C" void kernel_launch(void* const* d_in, const int* in_sizes, int n_in,
                              void* d_out, int out_size, void* d_ws, size_t ws_size,
                              hipStream_t stream) {
    const float* x_real  = (const float*)d_in[0];
    const float* x_imag  = (const float*)d_in[1];
    const float* qkv_wr  = (const float*)d_in[2];
    const float* qkv_wi  = (const float*)d_in[3];
    const float* proj_wr = (const float*)d_in[4];
    const float* proj_wi = (const float*)d_in[5];
    const float* rel     = (const float*)d_in[6];
    float* out = (float*)d_out;

    const int B = in_sizes[0] / 6144;

    if (ws_size >= (size_t)WS_NEED) {
        __half* wq      = (__half*)d_ws;
        __half* wpq     = (__half*)((char*)d_ws + WS_WP_OFF);
        float*  rel_exp = (float*)((char*)d_ws + WS_REL_OFF);
        prep_kernel<<<(WQ_ELEMS + 255) / 256, 256, 0, stream>>>(
            qkv_wr, qkv_wi, proj_wr, proj_wi, rel, wq, wpq, rel_exp);
        fused_kernel<<<B, BLOCK, 0, stream>>>(
            x_real, x_imag, wq, wpq, rel_exp, out);
    } else {
        cwattn_kernel<<<B, BLOCK, 0, stream>>>(
            x_real, x_imag, qkv_wr, qkv_wi, proj_wr, proj_wi, rel, out,
            (long long)out_size);
    }
}

// Round 3
// 262.292 us; speedup vs baseline: 2.1543x; 1.0742x over previous
//
#include <hip/hip_runtime.h>
#include <hip/hip_fp16.h>

// ComplexWindowAttn: B=2048 windows, DIM=96, HEADS=6, HEAD_DIM=16, N=64 (8x8).
// R10: fused kernel restructured for 2 blocks/CU (LDS 136 KB -> 66.5 KB).
//   - qkv cGEMM per round (2 heads/round, 3 rounds), x^T persistent in LDS.
//   - sA eliminated: softmax->PV handoff is within-wave; pack P[tm] (4 f16)
//     and exchange via ds_bpermute to build PV A-frags in registers
//     (target (l16,q) ks: e<4 from quad 2(q&1), e>=4 from 2(q&1)+1,
//      tile tm = 2ks+(q>>1), r = e&3 — derived from verified C-layout).
//   - rsqrt-based magnitude/softmax scaling (replaces sqrtf + div).
//   - __launch_bounds__(512,4) caps VGPR at 128 for 2-block residency.
// Fallback: verified R6 fused scalar kernel if ws too small.

#define HEADS 6
#define BLOCK 512
#define SCALE 0.25f

typedef _Float16 f16x8 __attribute__((ext_vector_type(8)));
typedef float    f32x4 __attribute__((ext_vector_type(4)));

#define WQ_ELEMS   27648              // 288*96 per plane
#define WS_WQ_B    165888             // 3 planes * 27648 * 2B
#define WS_WP_B    36864              // 96*192 f16
#define WS_REL_B   98304              // 6*64*64 f32
#define WS_WP_OFF  WS_WQ_B
#define WS_REL_OFF (WS_WQ_B + WS_WP_B)
#define WS_NEED    (WS_WQ_B + WS_WP_B + WS_REL_B)
#define XT_PITCH   104                // 96 + 8 pad (keeps 16B alignment)

// ===================== K1: weight/bias preparation =====================
__global__ void prep_kernel(const float* __restrict__ wr,
                            const float* __restrict__ wi,
                            const float* __restrict__ pwr,
                            const float* __restrict__ pwi,
                            const float* __restrict__ rel,
                            __half* __restrict__ wq,
                            __half* __restrict__ wp,
                            float* __restrict__ rel_exp)
{
    int i = blockIdx.x * 256 + threadIdx.x;
    if (i < WQ_ELEMS) {
        wq[i]                 = __float2half(wr[i]);
        wq[WQ_ELEMS + i]      = __float2half(wi[i]);
        wq[2 * WQ_ELEMS + i]  = __float2half(-wi[i]);
    }
    if (i < 9216) {                       // 96*96 proj weights -> packed
        int o = i / 96, c = i - o * 96;
        int h = c >> 4, d = c & 15;
        wp[o * 192 + h * 32 + d]      = __float2half(pwr[i]);
        wp[o * 192 + h * 32 + 16 + d] = __float2half(-pwi[i]);
    }
    if (i < 24576) {                      // rel -> TRANSPOSED [h][m][n]
        int h = i >> 12, m = (i >> 6) & 63, n = i & 63;
        int idx = ((n >> 3) - (m >> 3) + 7) * 15 + ((n & 7) - (m & 7) + 7);
        rel_exp[i] = rel[h * 225 + idx];
    }
}

// ===================== fused kernel =====================
// LDS map (f16 units), total 33280 f16 = 66560 B -> 2 blocks/CU:
//   xtr_r [64][104] @ 0      (6656)   persistent all rounds
//   xtr_i [64][104] @ 6656   (6656)
//   sQ  [2][64][40] @ 13312  (5120)   per-round, re@d im@16+d, *SCALE
//   sK  [2][64][40] @ 18432  (5120)
//   sVr [2][16][72] @ 23552  (2304)   [d][m]
//   sVi [2][16][72] @ 25856  (2304)
//   sO  [2][64][40] @ 28160  (5120)   Or@d, Oi@16+d
__global__ __launch_bounds__(BLOCK, 4) void fused_kernel(
    const float* __restrict__ x_real, const float* __restrict__ x_imag,
    const __half* __restrict__ wq,
    const __half* __restrict__ wp,
    const float* __restrict__ relT,
    float* __restrict__ out)
{
    __shared__ __align__(16) _Float16 smem[33280];

    _Float16* const xtr_r = smem;
    _Float16* const xtr_i = smem + 6656;
    _Float16* const sQ    = smem + 13312;
    _Float16* const sK    = smem + 18432;
    _Float16* const sVr   = smem + 23552;
    _Float16* const sVi   = smem + 25856;
    _Float16* const sO    = smem + 28160;

    const int b    = blockIdx.x;
    const int t    = threadIdx.x;
    const int lane = t & 63;
    const int w    = __builtin_amdgcn_readfirstlane(t >> 6);
    const int l16  = lane & 15;
    const int quad = lane >> 4;

    const float* xr = x_real + (size_t)b * 6144;   // [c][n]
    const float* xi = x_imag + (size_t)b * 6144;

    // ---------- phase 1: stage x^T (f16, B^T layout) ----------
    {
#pragma unroll
        for (int pass = 0; pass < 2; ++pass) {
            int n, cb;
            if (pass == 0) { n = t >> 3; cb = t & 7; }
            else           { if (t >= 256) break; n = t >> 2; cb = 8 + (t & 3); }
            const float* xrp = xr + cb * 512 + n;
            const float* xip = xi + cb * 512 + n;
            f16x8 vr, vi;
#pragma unroll
            for (int j = 0; j < 8; ++j) {
                vr[j] = (_Float16)xrp[j * 64];
                vi[j] = (_Float16)xip[j * 64];
            }
            *reinterpret_cast<f16x8*>(&xtr_r[n * XT_PITCH + cb * 8]) = vr;
            *reinterpret_cast<f16x8*>(&xtr_i[n * XT_PITCH + cb * 8]) = vi;
        }
    }
    __syncthreads();

    f32x4 pacc0 = {0.f,0.f,0.f,0.f};
    f32x4 pacc1 = {0.f,0.f,0.f,0.f};
    f32x4 pacc2 = {0.f,0.f,0.f,0.f};

    const _Float16* wpf = reinterpret_cast<const _Float16*>(wp);
    const __half* wr_p  = wq;
    const __half* wi_p  = wq + WQ_ELEMS;
    const __half* wni_p = wq + 2 * WQ_ELEMS;

    const int hr = w >> 2;          // head-in-round for attn (0/1)
    const int nb = w & 3;           // 16-col n-block for attn

    for (int ro = 0; ro < 3; ++ro) {
        // ---------- qkv cGEMM for heads 2ro, 2ro+1 ----------
        {
            int last_tile = -1;
            f16x8 a_r[3], a_i[3], a_ni[3];
#pragma unroll
            for (int ui = 0; ui < 3; ++ui) {
                const int u   = w * 3 + ui;      // 0..23
                const int ml  = u >> 2;          // 0..5
                const int nt  = u & 3;
                const int hl  = ml & 1;          // head-local
                const int mat = ml >> 1;         // 0=Q,1=K,2=V
                const int tile = mat * 6 + ro * 2 + hl;   // 16-row tile in W
                if (tile != last_tile) {
#pragma unroll
                    for (int ks = 0; ks < 3; ++ks) {
                        size_t off = (size_t)(tile * 16 + l16) * 96 + ks * 32 + quad * 8;
                        a_r[ks]  = *reinterpret_cast<const f16x8*>(wr_p  + off);
                        a_i[ks]  = *reinterpret_cast<const f16x8*>(wi_p  + off);
                        a_ni[ks] = *reinterpret_cast<const f16x8*>(wni_p + off);
                    }
                    last_tile = tile;
                }
                const int n0 = nt * 16;
                f16x8 b_r[3], b_i[3];
#pragma unroll
                for (int ks = 0; ks < 3; ++ks) {
                    int addr = (n0 + l16) * XT_PITCH + ks * 32 + quad * 8;
                    b_r[ks] = *reinterpret_cast<const f16x8*>(&xtr_r[addr]);
                    b_i[ks] = *reinterpret_cast<const f16x8*>(&xtr_i[addr]);
                }
                f32x4 accr = {0.f, 0.f, 0.f, 0.f};
                f32x4 acci = {0.f, 0.f, 0.f, 0.f};
#pragma unroll
                for (int ks = 0; ks < 3; ++ks) {
                    accr = __builtin_amdgcn_mfma_f32_16x16x32_f16(a_r[ks],  b_r[ks], accr, 0, 0, 0);
                    accr = __builtin_amdgcn_mfma_f32_16x16x32_f16(a_ni[ks], b_i[ks], accr, 0, 0, 0);
                    acci = __builtin_amdgcn_mfma_f32_16x16x32_f16(a_r[ks],  b_i[ks], acci, 0, 0, 0);
                    acci = __builtin_amdgcn_mfma_f32_16x16x32_f16(a_i[ks],  b_r[ks], acci, 0, 0, 0);
                }
                // C: col n = n0+l16, row d = quad*4 + r (verified layout)
                const int n = n0 + l16;
                if (mat == 0) {                 // Q, pre-scaled
                    _Float16* q = sQ + hl * 2560 + n * 40;
#pragma unroll
                    for (int r = 0; r < 4; ++r) {
                        q[quad * 4 + r]      = (_Float16)(accr[r] * SCALE);
                        q[16 + quad * 4 + r] = (_Float16)(acci[r] * SCALE);
                    }
                } else if (mat == 1) {          // K
                    _Float16* kk = sK + hl * 2560 + n * 40;
#pragma unroll
                    for (int r = 0; r < 4; ++r) {
                        kk[quad * 4 + r]      = (_Float16)accr[r];
                        kk[16 + quad * 4 + r] = (_Float16)acci[r];
                    }
                } else {                        // V -> [d][m]
#pragma unroll
                    for (int r = 0; r < 4; ++r) {
                        sVr[hl * 1152 + (quad * 4 + r) * 72 + n] = (_Float16)accr[r];
                        sVi[hl * 1152 + (quad * 4 + r) * 72 + n] = (_Float16)acci[r];
                    }
                }
            }
        }
        __syncthreads();                        // B1

        const int hl = hr;
        const int hh = ro * 2 + hr;

        // ---------- swapped scores: C[m][n], lane owns n = nb*16+l16 ----------
        float sr16[4][4], si16[4][4], mg16[4][4];
        float mx = -1e30f;
        {
            const _Float16* qrow = sQ + hl * 2560 + (nb * 16 + l16) * 40;
            f16x8 bq  = *reinterpret_cast<const f16x8*>(qrow + quad * 8);
            f16x8 bq2 = *reinterpret_cast<const f16x8*>(qrow + ((quad + 2) & 3) * 8);
            if (quad >= 2) bq2 = -bq2;          // [Qi | -Qr]
#pragma unroll
            for (int tm = 0; tm < 4; ++tm) {
                f16x8 ak = *reinterpret_cast<const f16x8*>(
                    sK + hl * 2560 + (tm * 16 + l16) * 40 + quad * 8);
                f32x4 fr = {0.f,0.f,0.f,0.f}, fi = {0.f,0.f,0.f,0.f};
                fr = __builtin_amdgcn_mfma_f32_16x16x32_f16(ak, bq,  fr, 0, 0, 0);
                fi = __builtin_amdgcn_mfma_f32_16x16x32_f16(ak, bq2, fi, 0, 0, 0);
#pragma unroll
                for (int r = 0; r < 4; ++r) {
                    const int m = tm * 16 + quad * 4 + r;
                    float bb  = relT[hh * 4096 + m * 64 + nb * 16 + l16];
                    float vr_ = fr[r] + bb;
                    float vi_ = fi[r];
                    sr16[tm][r] = vr_; si16[tm][r] = vi_;
                    float m2  = fmaf(vr_, vr_, vi_ * vi_);
                    float rs  = __frsqrt_rn(m2 + 1e-16f);
                    float mag = m2 * rs;        // == sqrt(m2), 0 at m2=0
                    mg16[tm][r] = mag;
                    mx = fmaxf(mx, mag);
                }
            }
        }
        mx = fmaxf(mx, __shfl_xor(mx, 16));
        mx = fmaxf(mx, __shfl_xor(mx, 32));
        float ss = 0.f;
#pragma unroll
        for (int tm = 0; tm < 4; ++tm)
#pragma unroll
            for (int r = 0; r < 4; ++r)
                ss += __expf(mg16[tm][r] - mx);
        ss += __shfl_xor(ss, 16);
        ss += __shfl_xor(ss, 32);
        const float inv = 1.0f / ss;

        // ---------- pack P[tm] (4 f16 per plane) ----------
        uint2 Pr[4], Pi[4];
#pragma unroll
        for (int tm = 0; tm < 4; ++tm) {
            float f_[4];
#pragma unroll
            for (int r = 0; r < 4; ++r) {
                float mag = mg16[tm][r];
                float rs  = __frsqrt_rn(fmaf(mag, mag, 1e-16f));
                f_[r] = __expf(mag - mx) * inv * rs;
            }
            __half2 r01 = __floats2half2_rn(sr16[tm][0]*f_[0], sr16[tm][1]*f_[1]);
            __half2 r23 = __floats2half2_rn(sr16[tm][2]*f_[2], sr16[tm][3]*f_[3]);
            __half2 i01 = __floats2half2_rn(si16[tm][0]*f_[0], si16[tm][1]*f_[1]);
            __half2 i23 = __floats2half2_rn(si16[tm][2]*f_[2], si16[tm][3]*f_[3]);
            Pr[tm].x = *reinterpret_cast<unsigned*>(&r01);
            Pr[tm].y = *reinterpret_cast<unsigned*>(&r23);
            Pi[tm].x = *reinterpret_cast<unsigned*>(&i01);
            Pi[tm].y = *reinterpret_cast<unsigned*>(&i23);
        }

        // ---------- exchange -> PV A-frags, then PV MFMA ----------
        {
            const int srcA = (l16 + ((quad & 1) << 5)) << 2;
            const int srcB = srcA + 64;
            const bool hiq = (quad >= 2);
            union FU { unsigned u[4]; f16x8 v; };
            f32x4 oar = {0.f,0.f,0.f,0.f}, oai = {0.f,0.f,0.f,0.f};
#pragma unroll
            for (int ks = 0; ks < 2; ++ks) {
                FU fr_, fi_;
                {
                    unsigned a0 = __builtin_amdgcn_ds_bpermute(srcA, (int)Pr[2*ks].x);
                    unsigned a1 = __builtin_amdgcn_ds_bpermute(srcA, (int)Pr[2*ks].y);
                    unsigned a2 = __builtin_amdgcn_ds_bpermute(srcA, (int)Pr[2*ks+1].x);
                    unsigned a3 = __builtin_amdgcn_ds_bpermute(srcA, (int)Pr[2*ks+1].y);
                    unsigned b0 = __builtin_amdgcn_ds_bpermute(srcB, (int)Pr[2*ks].x);
                    unsigned b1 = __builtin_amdgcn_ds_bpermute(srcB, (int)Pr[2*ks].y);
                    unsigned b2 = __builtin_amdgcn_ds_bpermute(srcB, (int)Pr[2*ks+1].x);
                    unsigned b3 = __builtin_amdgcn_ds_bpermute(srcB, (int)Pr[2*ks+1].y);
                    fr_.u[0] = hiq ? a2 : a0;  fr_.u[1] = hiq ? a3 : a1;
                    fr_.u[2] = hiq ? b2 : b0;  fr_.u[3] = hiq ? b3 : b1;
                }
                {
                    unsigned a0 = __builtin_amdgcn_ds_bpermute(srcA, (int)Pi[2*ks].x);
                    unsigned a1 = __builtin_amdgcn_ds_bpermute(srcA, (int)Pi[2*ks].y);
                    unsigned a2 = __builtin_amdgcn_ds_bpermute(srcA, (int)Pi[2*ks+1].x);
                    unsigned a3 = __builtin_amdgcn_ds_bpermute(srcA, (int)Pi[2*ks+1].y);
                    unsigned b0 = __builtin_amdgcn_ds_bpermute(srcB, (int)Pi[2*ks].x);
                    unsigned b1 = __builtin_amdgcn_ds_bpermute(srcB, (int)Pi[2*ks].y);
                    unsigned b2 = __builtin_amdgcn_ds_bpermute(srcB, (int)Pi[2*ks+1].x);
                    unsigned b3 = __builtin_amdgcn_ds_bpermute(srcB, (int)Pi[2*ks+1].y);
                    fi_.u[0] = hiq ? a2 : a0;  fi_.u[1] = hiq ? a3 : a1;
                    fi_.u[2] = hiq ? b2 : b0;  fi_.u[3] = hiq ? b3 : b1;
                }
                const int ko = ks * 32 + quad * 8;
                f16x8 vr_ = *reinterpret_cast<const f16x8*>(&sVr[hl * 1152 + l16 * 72 + ko]);
                f16x8 vi_ = *reinterpret_cast<const f16x8*>(&sVi[hl * 1152 + l16 * 72 + ko]);
                oar = __builtin_amdgcn_mfma_f32_16x16x32_f16(fr_.v,  vr_,  oar, 0, 0, 0);
                oar = __builtin_amdgcn_mfma_f32_16x16x32_f16(fi_.v, -vi_,  oar, 0, 0, 0);
                oai = __builtin_amdgcn_mfma_f32_16x16x32_f16(fr_.v,  vi_,  oai, 0, 0, 0);
                oai = __builtin_amdgcn_mfma_f32_16x16x32_f16(fi_.v,  vr_,  oai, 0, 0, 0);
            }
#pragma unroll
            for (int r = 0; r < 4; ++r) {
                const int n = nb * 16 + quad * 4 + r;
                sO[hl * 2560 + n * 40 + l16]      = (_Float16)oar[r];
                sO[hl * 2560 + n * 40 + 16 + l16] = (_Float16)oai[r];
            }
        }
        __syncthreads();                        // B2

        // ---------- proj accumulate (R9-verified math) ----------
        {
            const int ob0 = (w & 1) * 3;
            const int pnb = w >> 1;
#pragma unroll
            for (int h2 = 0; h2 < 2; ++h2) {
                const _Float16* wb = wpf + (ro * 2 + h2) * 32 + quad * 8;
                f16x8 wb0 = *reinterpret_cast<const f16x8*>(wb + ((ob0    ) * 16 + l16) * 192);
                f16x8 wb1 = *reinterpret_cast<const f16x8*>(wb + ((ob0 + 1) * 16 + l16) * 192);
                f16x8 wb2 = *reinterpret_cast<const f16x8*>(wb + ((ob0 + 2) * 16 + l16) * 192);
                f16x8 a = *reinterpret_cast<const f16x8*>(
                    &sO[h2 * 2560 + (pnb * 16 + l16) * 40 + quad * 8]);
                pacc0 = __builtin_amdgcn_mfma_f32_16x16x32_f16(a, wb0, pacc0, 0, 0, 0);
                pacc1 = __builtin_amdgcn_mfma_f32_16x16x32_f16(a, wb1, pacc1, 0, 0, 0);
                pacc2 = __builtin_amdgcn_mfma_f32_16x16x32_f16(a, wb2, pacc2, 0, 0, 0);
            }
        }
        // next round's qkv writes (sQ/sK/sV) are disjoint from sO reads here;
        // B1 of the next round orders proj reads before the next sO writes.
    }

    // ---------- epilogue: out[o][n], o = (w&1)*48 + j*16 + l16 ----------
    {
        float* op = out + (size_t)b * 6144 + ((w & 1) * 48 + l16) * 64
                  + (w >> 1) * 16 + quad * 4;
        *reinterpret_cast<f32x4*>(op)        = pacc0;
        *reinterpret_cast<f32x4*>(op + 1024) = pacc1;
        *reinterpret_cast<f32x4*>(op + 2048) = pacc2;
    }
}

// ===================== Fallback: verified R6 fused kernel =====================
__global__ __launch_bounds__(BLOCK) void cwattn_kernel(
    const float* __restrict__ x_real, const float* __restrict__ x_imag,
    const float* __restrict__ qkv_wr, const float* __restrict__ qkv_wi,
    const float* __restrict__ proj_wr, const float* __restrict__ proj_wi,
    const float* __restrict__ rel, float* __restrict__ out,
    long long out_elems)
{
    __shared__ float2 qs[16 * 64];
    __shared__ float2 ks[16 * 64];
    __shared__ float2 vs[16 * 64];
    __shared__ float2 outh[16 * 64];

    const int b    = blockIdx.x;
    const int t    = threadIdx.x;
    const int lane = t & 63;
    const int wave = __builtin_amdgcn_readfirstlane(t >> 6);

    const float* xr = x_real + (size_t)b * 6144;
    const float* xi = x_imag + (size_t)b * 6144;

    float yr[12], yi[12];
#pragma unroll
    for (int j = 0; j < 12; ++j) { yr[j] = 0.f; yi[j] = 0.f; }

    const int g  = t >> 3;
    const int mo = t & 7;
    const int m0 = mo * 8;
    const int gi = g >> 3, gj = g & 7;

    for (int h = 0; h < HEADS; ++h) {
        {
            float ar[6], ai[6];
#pragma unroll
            for (int j = 0; j < 6; ++j) { ar[j] = 0.f; ai[j] = 0.f; }
            const int r0 = wave * 6;
            const float* wrp[6]; const float* wip[6];
#pragma unroll
            for (int j = 0; j < 6; ++j) {
                int r = r0 + j;
                int s = r >> 4;
                int o = s * 96 + h * 16 + (r & 15);
                wrp[j] = qkv_wr + o * 96;
                wip[j] = qkv_wi + o * 96;
            }
#pragma unroll 4
            for (int c = 0; c < 96; ++c) {
                float xre = xr[c * 64 + lane];
                float xim = xi[c * 64 + lane];
#pragma unroll
                for (int j = 0; j < 6; ++j) {
                    float wr = wrp[j][c], wi = wip[j][c];
                    ar[j] = fmaf(wr, xre, fmaf(-wi, xim, ar[j]));
                    ai[j] = fmaf(wr, xim, fmaf( wi, xre, ai[j]));
                }
            }
#pragma unroll
            for (int j = 0; j < 6; ++j) {
                int r  = r0 + j;
                int s  = r >> 4;
                int rd = r & 15;
                float scl   = (s == 0) ? SCALE : 1.0f;
                float2* dst = (s == 0) ? qs : ((s == 1) ? ks : vs);
                dst[rd * 64 + lane] = make_float2(ar[j] * scl, ai[j] * scl);
            }
        }
        __syncthreads();
        {
            float sr[8], si[8];
#pragma unroll
            for (int j = 0; j < 8; ++j) { sr[j] = 0.f; si[j] = 0.f; }
            for (int d = 0; d < 16; ++d) {
                float2 q2 = qs[d * 64 + g];
#pragma unroll
                for (int j = 0; j < 8; ++j) {
                    float2 k2 = ks[d * 64 + m0 + j];
                    sr[j] = fmaf(q2.x, k2.x, fmaf( q2.y, k2.y, sr[j]));
                    si[j] = fmaf(q2.y, k2.x, fmaf(-q2.x, k2.y, si[j]));
                }
            }
            const float* relh = rel + h * 225;
            float mag[8], e[8];
            float mx = -1e30f;
#pragma unroll
            for (int j = 0; j < 8; ++j) {
                int m = m0 + j;
                int idx = (gi - (m >> 3) + 7) * 15 + (gj - (m & 7) + 7);
                sr[j] += relh[idx];
                mag[j] = sqrtf(fmaf(sr[j], sr[j], si[j] * si[j]));
                mx = fmaxf(mx, mag[j]);
            }
            mx = fmaxf(mx, __shfl_xor(mx, 1));
            mx = fmaxf(mx, __shfl_xor(mx, 2));
            mx = fmaxf(mx, __shfl_xor(mx, 4));
            float ssum = 0.f;
#pragma unroll
            for (int j = 0; j < 8; ++j) { e[j] = __expf(mag[j] - mx); ssum += e[j]; }
            ssum += __shfl_xor(ssum, 1);
            ssum += __shfl_xor(ssum, 2);
            ssum += __shfl_xor(ssum, 4);
            float isum = 1.0f / ssum;
#pragma unroll
            for (int j = 0; j < 8; ++j) {
                float f = e[j] * isum / (mag[j] + 1e-8f);
                sr[j] *= f; si[j] *= f;
            }
            for (int d = 0; d < 16; ++d) {
                float pr = 0.f, pi = 0.f;
#pragma unroll
                for (int j = 0; j < 8; ++j) {
                    float2 v2 = vs[d * 64 + m0 + j];
                    pr = fmaf(sr[j], v2.x, fmaf(-si[j], v2.y, pr));
                    pi = fmaf(sr[j], v2.y, fmaf( si[j], v2.x, pi));
                }
                pr += __shfl_xor(pr, 1); pr += __shfl_xor(pr, 2); pr += __shfl_xor(pr, 4);
                pi += __shfl_xor(pi, 1); pi += __shfl_xor(pi, 2); pi += __shfl_xor(pi, 4);
                if (mo == 0) outh[d * 64 + g] = make_float2(pr, pi);
            }
        }
        __syncthreads();
        {
            const float* pr0 = proj_wr + (wave * 12) * 96 + h * 16;
            const float* pi0 = proj_wi + (wave * 12) * 96 + h * 16;
            for (int d = 0; d < 16; ++d) {
                float2 o2 = outh[d * 64 + lane];
#pragma unroll
                for (int j = 0; j < 12; ++j) {
                    float wr = pr0[j * 96 + d];
                    float wi = pi0[j * 96 + d];
                    yr[j] = fmaf(wr, o2.x, fmaf(-wi, o2.y, yr[j]));
                    yi[j] = fmaf(wr, o2.y, fmaf( wi, o2.x, yi[j]));
                }
            }
        }
        __syncthreads();
    }

    const long long n_total = (long long)gridDim.x * 6144;
#pragma unroll
    for (int j = 0; j < 12; ++j) {
        int o = wave * 12 + j;
        long long ci = (long long)b * 6144 + o * 64 + lane;
        if (ci < out_elems)           out[ci]           = yr[j];
        if (n_total + ci < out_elems) out[n_total + ci] = yi[j];
    }
}

// ===================== host =====================
extern "C" void kernel_launch(void* const* d_in, const int* in_sizes, int n_in,
                              void* d_out, int out_size, void* d_ws, size_t ws_size,
                              hipStream_t stream) {
    const float* x_real  = (const float*)d_in[0];
    const float* x_imag  = (const float*)d_in[1];
    const float* qkv_wr  = (const float*)d_in[2];
    const float* qkv_wi  = (const float*)d_in[3];
    const float* proj_wr = (const float*)d_in[4];
    const float* proj_wi = (const float*)d_in[5];
    const float* rel     = (const float*)d_in[6];
    float* out = (float*)d_out;

    const int B = in_sizes[0] / 6144;

    if (ws_size >= (size_t)WS_NEED) {
        __half* wq      = (__half*)d_ws;
        __half* wpq     = (__half*)((char*)d_ws + WS_WP_OFF);
        float*  rel_exp = (float*)((char*)d_ws + WS_REL_OFF);
        prep_kernel<<<(WQ_ELEMS + 255) / 256, 256, 0, stream>>>(
            qkv_wr, qkv_wi, proj_wr, proj_wi, rel, wq, wpq, rel_exp);
        fused_kernel<<<B, BLOCK, 0, stream>>>(
            x_real, x_imag, wq, wpq, rel_exp, out);
    } else {
        cwattn_kernel<<<B, BLOCK, 0, stream>>>(
            x_real, x_imag, qkv_wr, qkv_wi, proj_wr, proj_wi, rel, out,
            (long long)out_size);
    }
}